// Round 5
// baseline (228.341 us; speedup 1.0000x reference)
//
#include <hip/hip_runtime.h>

typedef __bf16 bf16;
typedef __bf16 bf16x8 __attribute__((ext_vector_type(8)));
typedef float f32x4 __attribute__((ext_vector_type(4)));
typedef int i32x8 __attribute__((ext_vector_type(8)));
typedef unsigned int u32;
typedef unsigned char u8;

#define N_TOK 9216
#define SRC 1024
#define EDIM 256
#define NE 16384
#define NSLAB 32   // 32 slabs of 512 codes
#define SLAB 512
#define NBLK_LOSS 144
#define NEG_CB_SCALE -8192.0f
#define E2_SCALE 4096.0f
#define LOSS_DENOM 2359296.0f  // 16*576*256

__device__ __forceinline__ void async_load16(const void* g, void* l) {
  __builtin_amdgcn_global_load_lds(
      (__attribute__((address_space(1))) void*)(void*)(const_cast<void*>(g)),
      (__attribute__((address_space(3))) void*)l, 16, 0, 0);
}

__device__ __forceinline__ f32x4 mfma16(bf16x8 a, bf16x8 b, f32x4 c) {
  return __builtin_amdgcn_mfma_f32_16x16x32_bf16(a, b, c, 0, 0, 0);
}
// MX-scaled fp8 K=128; scale bytes 0x7F = 2^0 = 1.0; cbsz/blgp 0 = fp8 e4m3
__device__ __forceinline__ f32x4 mfma_mx(i32x8 a, i32x8 b, f32x4 c) {
  return __builtin_amdgcn_mfma_scale_f32_16x16x128_f8f6f4(
      a, b, c, 0, 0, 0, 0x7F7F7F7F, 0, 0x7F7F7F7F);
}

// ---------------- prep: coalesced 64x64 LDS transposes + fp8 codebook -------
// b<64: enc_w [1024,256] -> enc_wT [256,1024]; b<128: dec_w [256,1024] ->
// dec_wT [1024,256]; else codebook (negated fp8, fragment-major swizzle) + e2s.
__global__ __launch_bounds__(256) void k_prep(const float* __restrict__ enc_w,
                                              const float* __restrict__ dec_w,
                                              const float* __restrict__ cb,
                                              bf16* __restrict__ enc_wT,
                                              bf16* __restrict__ dec_wT,
                                              u32* __restrict__ cbb8,
                                              float* __restrict__ e2s) {
  int b = blockIdx.x;
  if (b < 128) {
    __shared__ float T[64][65];
    const float* In;
    bf16* Out;
    int R, C, ti, tj;
    if (b < 64) {  // enc: In 1024x256, tiles 16(k) x 4(n)
      In = enc_w; Out = enc_wT; R = 1024; C = 256;
      ti = b & 15; tj = b >> 4;
    } else {       // dec: In 256x1024, tiles 4(k) x 16(n)
      int t2 = b - 64;
      In = dec_w; Out = dec_wT; R = 256; C = 1024;
      ti = t2 & 3; tj = t2 >> 2;
    }
    int c0 = threadIdx.x & 63, r0 = threadIdx.x >> 6;
#pragma unroll
    for (int i = 0; i < 16; i++) {
      int rr = r0 + i * 4;
      T[rr][c0] = In[(size_t)(ti * 64 + rr) * C + tj * 64 + c0];
    }
    __syncthreads();
#pragma unroll
    for (int i = 0; i < 16; i++) {
      int rr = r0 + i * 4;
      Out[(size_t)(tj * 64 + rr) * R + ti * 64 + c0] = (bf16)T[c0][rr];
    }
  } else {
    // codebook row r: stored slot s holds source granule h=(s&8)|((s&7)^(r&7)),
    // scaled by -8192 (negated -> distance epilogue is the MFMA acc itself).
    int row = (b - 128) * 4 + (threadIdx.x >> 6);
    int lane = threadIdx.x & 63;
    int slot = lane >> 2;
    int h = (slot & 8) | ((slot & 7) ^ (row & 7));
    int k0 = h * 16 + (lane & 3) * 4;
    float4 v = *(const float4*)(cb + (size_t)row * EDIM + k0);
    int pk = __builtin_amdgcn_cvt_pk_fp8_f32(v.x * NEG_CB_SCALE, v.y * NEG_CB_SCALE, 0, false);
    pk = __builtin_amdgcn_cvt_pk_fp8_f32(v.z * NEG_CB_SCALE, v.w * NEG_CB_SCALE, pk, true);
    cbb8[(size_t)row * 64 + lane] = (u32)pk;
    float sq = v.x * v.x + v.y * v.y + v.z * v.z + v.w * v.w;
#pragma unroll
    for (int off = 32; off; off >>= 1) sq += __shfl_xor(sq, off, 64);
    if (lane == 0) e2s[row] = E2_SCALE * (sq + 1.0f);
  }
}

// ---------------- encoder GEMM: 64x64 tile, fused f32->bf16, fp8 out --------
// z = x @ enc_wT^T + enc_b. grid (144,4). 4 waves 2x2, wave tile 32x32.
// f32 A-loads issued AFTER the barrier so barriers drain only old async loads.
__global__ __launch_bounds__(256) void k_enc(const float* __restrict__ x,
                                             const bf16* __restrict__ wT,
                                             const float* __restrict__ bias,
                                             u8* __restrict__ z8) {
  __shared__ __align__(16) bf16 As[2][64 * 32];
  __shared__ __align__(16) bf16 Bs[2][64 * 32];
  const int tid = threadIdx.x;
  const int wid = tid >> 6, lane = tid & 63;
  const int col = lane & 15, quad = lane >> 4;
  const int wm = (wid >> 1) * 32, wn = (wid & 1) * 32;
  const int bm = blockIdx.x * 64, bn = blockIdx.y * 64;
  f32x4 acc[2][2] = {};
  const int arow = tid >> 2, ags = tid & 3;

  float4 q0, q1;
  auto loadA = [&](int kc) {
    const float* p = x + (size_t)(bm + arow) * SRC + kc + ags * 8;
    q0 = *(const float4*)p;
    q1 = *(const float4*)(p + 4);
  };
  auto writeA = [&](int bb) {
    bf16x8 o = {(bf16)q0.x, (bf16)q0.y, (bf16)q0.z, (bf16)q0.w,
                (bf16)q1.x, (bf16)q1.y, (bf16)q1.z, (bf16)q1.w};
    *(bf16x8*)((char*)&As[bb][0] + (arow * 4 + (ags ^ (arow & 3))) * 16) = o;
  };
  auto stageB = [&](int kc, int bb) {
    int row = tid >> 2;
    int gg = (tid & 3) ^ (row & 3);
    async_load16(wT + (size_t)(bn + row) * SRC + kc + gg * 8,
                 (char*)&Bs[bb][0] + wid * 1024);
  };

  loadA(0);
  writeA(0);
  stageB(0, 0);
  for (int it = 0; it < 32; it++) {
    int cbuf = it & 1, nbuf = cbuf ^ 1;
    __syncthreads();
    if (it < 31) {
      loadA((it + 1) * 32);
      stageB((it + 1) * 32, nbuf);
    }
    bf16x8 afr[2], bfr[2];
#pragma unroll
    for (int t = 0; t < 2; t++) {
      int row = wm + t * 16 + col;
      afr[t] = *(const bf16x8*)((const char*)&As[cbuf][0] +
                                (row * 4 + (quad ^ (row & 3))) * 16);
    }
#pragma unroll
    for (int u = 0; u < 2; u++) {
      int row = wn + u * 16 + col;
      bfr[u] = *(const bf16x8*)((const char*)&Bs[cbuf][0] +
                                (row * 4 + (quad ^ (row & 3))) * 16);
    }
#pragma unroll
    for (int t = 0; t < 2; t++)
#pragma unroll
      for (int u = 0; u < 2; u++) acc[t][u] = mfma16(afr[t], bfr[u], acc[t][u]);
    if (it < 31) writeA(nbuf);
  }
#pragma unroll
  for (int u = 0; u < 2; u++) {
    int n = bn + wn + u * 16 + col;
    float bv = bias[n];
#pragma unroll
    for (int t = 0; t < 2; t++)
#pragma unroll
      for (int r = 0; r < 4; r++) {
        int m = bm + wm + t * 16 + quad * 4 + r;
        float v = acc[t][u][r] + bv;
        int pk = __builtin_amdgcn_cvt_pk_fp8_f32(v, v, 0, false);
        z8[(size_t)m * EDIM + n] = (u8)(pk & 0xFF);
      }
  }
}

// ---------------- fused MX-fp8 cross-GEMM + argmin v12 ----------------
// v12 = v8 structure exactly (4 waves x 48 tokens, 64-code stages, 4-phase
// barriers, per-phase key/min epilogue), but each block handles a 512-code
// SLAB (8 stages) instead of a 1024-code group: grid (32,48) = 1536 blocks,
// __launch_bounds__(256,4) -> 4 blocks/CU resident (16 waves/CU vs v8's 12).
// R4 lesson: dur tracks occupancy (barrier-drain overlap), not per-wave LDS
// traffic -> raise residency at constant per-wave structure.
__global__ __launch_bounds__(256, 4) void k_argmin(const u8* __restrict__ zb8,
                                                   const u8* __restrict__ cbb8,
                                                   const float* __restrict__ e2s,
                                                   float* __restrict__ pval,
                                                   int* __restrict__ pidx) {
  __shared__ __align__(16) u8 Cs[2 * 16384];
  __shared__ __align__(16) float Es[SLAB];
  const int tid = threadIdx.x;
  const int wid = tid >> 6, lane = tid & 63;
  const int col = lane & 15, quad = lane >> 4;
  const int g = blockIdx.x;  // slab id [0,32)
  const int tw = blockIdx.y * 192 + wid * 48;

  // e2s for this slab -> LDS (2 KB: waves 0,1 only)
  if (wid < 2)
    async_load16((const u8*)(e2s + g * SLAB) + (size_t)tid * 16,
                 (char*)Es + wid * 1024);

  i32x8 af[3][2];
#pragma unroll
  for (int t = 0; t < 3; t++)
#pragma unroll
    for (int m = 0; m < 2; m++) {
      const u8* p = zb8 + (size_t)(tw + t * 16 + col) * EDIM + m * 128 + quad * 32;
      int4 lo = *(const int4*)p;
      int4 hi = *(const int4*)(p + 16);
      af[t][m] = (i32x8){lo.x, lo.y, lo.z, lo.w, hi.x, hi.y, hi.z, hi.w};
    }

  u32 best[3][4];
#pragma unroll
  for (int t = 0; t < 3; t++)
#pragma unroll
    for (int r = 0; r < 4; r++) best[t][r] = 0xFFFFFFFFu;

  auto stage_load = [&](int st, int bb) {
    const u8* src = cbb8 + (size_t)(g * SLAB + st * 64) * EDIM;
#pragma unroll
    for (int j = 0; j < 4; j++) {
      async_load16(src + (wid * 256 + j * 64 + lane) * 16,
                   (char*)Cs + bb * 16384 + wid * 4096 + j * 1024);
    }
  };

  stage_load(0, 0);
  asm volatile("s_waitcnt vmcnt(0)" ::: "memory");
  __builtin_amdgcn_s_barrier();

  const int r7 = col & 7;
  const int s0 = ((2 * quad) ^ r7) * 16;
  const int s1 = ((2 * quad + 1) ^ r7) * 16;

  for (int st = 0; st < 8; st++) {
    const char* bbase = (const char*)Cs + (st & 1) * 16384;
#pragma unroll
    for (int u = 0; u < 4; u++) {
      // ---- phase u: LDS reads for this quadrant (issued before the barrier,
      // completed by the lgkmcnt(0) after it -> latency spans the barrier)
      const int rb = (u * 16 + col) * 256;
      int4 a0 = *(const int4*)(bbase + rb + s0);
      int4 a1 = *(const int4*)(bbase + rb + s1);
      int4 b0 = *(const int4*)(bbase + rb + 128 + s0);
      int4 b1 = *(const int4*)(bbase + rb + 128 + s1);
      float ev = Es[st * 64 + u * 16 + col];
      // prefetch next stage: phase 1 only (phase-0 barrier proves all waves
      // finished reading this buffer in stage st-1)
      if (u == 1 && st < 7) stage_load(st + 1, (st & 1) ^ 1);
      __builtin_amdgcn_s_barrier();
      asm volatile("s_waitcnt lgkmcnt(0)" ::: "memory");
      __builtin_amdgcn_sched_barrier(0);
      __builtin_amdgcn_s_setprio(1);
      i32x8 bm0 = (i32x8){a0.x, a0.y, a0.z, a0.w, a1.x, a1.y, a1.z, a1.w};
      i32x8 bm1 = (i32x8){b0.x, b0.y, b0.z, b0.w, b1.x, b1.y, b1.z, b1.w};
      f32x4 c0 = (f32x4){ev, ev, ev, ev};
      f32x4 c1 = c0, c2 = c0;
      c0 = mfma_mx(af[0][0], bm0, c0);
      c1 = mfma_mx(af[1][0], bm0, c1);
      c2 = mfma_mx(af[2][0], bm0, c2);
      c0 = mfma_mx(af[0][1], bm1, c0);
      c1 = mfma_mx(af[1][1], bm1, c1);
      c2 = mfma_mx(af[2][1], bm1, c2);
      __builtin_amdgcn_s_setprio(0);
      // per-phase epilogue: one key per (t,r) this quadrant; overlaps next
      // phase's ds_reads
      const u32 code = (u32)(st * 4 + u);  // [0,32): 5 bits
#pragma unroll
      for (int r = 0; r < 4; r++) {
        u32 k0 = (__float_as_uint(c0[r]) & 0xFFFFFFC0u) | code;
        u32 k1 = (__float_as_uint(c1[r]) & 0xFFFFFFC0u) | code;
        u32 k2 = (__float_as_uint(c2[r]) & 0xFFFFFFC0u) | code;
        best[0][r] = k0 < best[0][r] ? k0 : best[0][r];
        best[1][r] = k1 < best[1][r] ? k1 : best[1][r];
        best[2][r] = k2 < best[2][r] ? k2 : best[2][r];
      }
    }
    // drain own prefetch (issued 3 phases ago), then end-of-stage barrier:
    // after it, ALL waves' loads for st+1 have landed.
    if (st < 7) asm volatile("s_waitcnt vmcnt(0)" ::: "memory");
    __builtin_amdgcn_s_barrier();
  }

#pragma unroll
  for (int t = 0; t < 3; t++)
#pragma unroll
    for (int r = 0; r < 4; r++) {
      u32 key = best[t][r];
      int cw = col;
#pragma unroll
      for (int off = 1; off < 16; off <<= 1) {
        u32 ok = (u32)__shfl_xor((int)key, off, 64);
        int oc = __shfl_xor(cw, off, 64);
        if (ok < key) { key = ok; cw = oc; }
      }
      if (col == 0) {
        int token = tw + t * 16 + quad * 4 + r;
        pval[token * NSLAB + g] = __uint_as_float(key & 0xFFFFFFC0u);
        pidx[token * NSLAB + g] = g * SLAB + (int)(key & 63u) * 16 + cw;
      }
    }
}

// ---------------- decoder GEMM with fused gather + loss ----------------
// out = cb[idx] @ dec_wT^T + dec_b. grid (144,4), 64 tokens x 256 cols.
// Phase 0: per-token argmin combine (4 lanes/token, 8 slabs each). Phase 1:
// K-loop; A-side gathers cb rows f32 (LLC) -> bf16 -> LDS.
// by==0 blocks also accumulate the loss partial (vs fp8 z).
__global__ __launch_bounds__(256) void k_dec(const float* __restrict__ cb,
                                             const float* __restrict__ pval,
                                             const int* __restrict__ pidx,
                                             const u8* __restrict__ zb8,
                                             const bf16* __restrict__ wT,
                                             const float* __restrict__ bias,
                                             float* __restrict__ out,
                                             float* __restrict__ lpart) {
  __shared__ __align__(16) bf16 As[2][64 * 32];
  __shared__ __align__(16) bf16 Bs[2][256 * 32];
  __shared__ int idxL[64];
  __shared__ float lsred[4];
  const int tid = threadIdx.x;
  const int wid = tid >> 6, lane = tid & 63;
  const int col = lane & 15, quad = lane >> 4;
  const int wm = (wid >> 1) * 32, wn = (wid & 1) * 128;
  const int bm = blockIdx.x * 64, bn = blockIdx.y * 256;
  const bool do_loss = (blockIdx.y == 0);

  // ---- phase 0: combine the 32 slab candidates for this block's 64 tokens
  {
    int tl = tid >> 2, j0 = tid & 3;
    float v = 3.4e38f;
    int idx = 0;
#pragma unroll
    for (int jj = 0; jj < 8; jj++) {
      int grp = j0 * 8 + jj;
      float ov = pval[(bm + tl) * NSLAB + grp];
      int oi = pidx[(bm + tl) * NSLAB + grp];
      if (ov < v || (ov == v && oi < idx)) { v = ov; idx = oi; }
    }
#pragma unroll
    for (int off = 1; off < 4; off <<= 1) {
      float ov = __shfl_xor(v, off, 64);
      int oi = __shfl_xor(idx, off, 64);
      if (ov < v || (ov == v && oi < idx)) { v = ov; idx = oi; }
    }
    if (j0 == 0) idxL[tl] = idx;
  }
  __syncthreads();

  const int arow = tid >> 2, ags = tid & 3;
  const int ridx = idxL[arow];
  float lacc = 0.f;
  f32x4 acc[2][8] = {};

  float4 q0, q1;
  auto loadA = [&](int kc) {
    const float* p = cb + (size_t)ridx * EDIM + kc + ags * 8;
    q0 = *(const float4*)p;
    q1 = *(const float4*)(p + 4);
    if (do_loss) {
      u32 zw0 = *(const u32*)(zb8 + (size_t)(bm + arow) * EDIM + kc + ags * 8);
      u32 zw1 = *(const u32*)(zb8 + (size_t)(bm + arow) * EDIM + kc + ags * 8 + 4);
      float d0 = q0.x - __builtin_amdgcn_cvt_f32_fp8(zw0, 0);
      float d1 = q0.y - __builtin_amdgcn_cvt_f32_fp8(zw0, 1);
      float d2 = q0.z - __builtin_amdgcn_cvt_f32_fp8(zw0, 2);
      float d3 = q0.w - __builtin_amdgcn_cvt_f32_fp8(zw0, 3);
      float d4 = q1.x - __builtin_amdgcn_cvt_f32_fp8(zw1, 0);
      float d5 = q1.y - __builtin_amdgcn_cvt_f32_fp8(zw1, 1);
      float d6 = q1.z - __builtin_amdgcn_cvt_f32_fp8(zw1, 2);
      float d7 = q1.w - __builtin_amdgcn_cvt_f32_fp8(zw1, 3);
      lacc += d0 * d0 + d1 * d1 + d2 * d2 + d3 * d3 +
              d4 * d4 + d5 * d5 + d6 * d6 + d7 * d7;
    }
  };
  auto writeA = [&](int bb) {
    bf16x8 o = {(bf16)q0.x, (bf16)q0.y, (bf16)q0.z, (bf16)q0.w,
                (bf16)q1.x, (bf16)q1.y, (bf16)q1.z, (bf16)q1.w};
    *(bf16x8*)((char*)&As[bb][0] + (arow * 4 + (ags ^ (arow & 3))) * 16) = o;
  };
  auto stageB = [&](int kc, int bb) {
#pragma unroll
    for (int j = 0; j < 4; j++) {
      int slot = wid * 256 + j * 64 + lane;
      int row = slot >> 2;
      int gg = (slot & 3) ^ (row & 3);
      async_load16(wT + (size_t)(bn + row) * EDIM + kc + gg * 8,
                   (char*)&Bs[bb][0] + wid * 4096 + j * 1024);
    }
  };

  loadA(0);
  writeA(0);
  stageB(0, 0);
  for (int it = 0; it < 8; it++) {
    int cbuf = it & 1, nbuf = cbuf ^ 1;
    __syncthreads();
    if (it < 7) {
      loadA((it + 1) * 32);
      stageB((it + 1) * 32, nbuf);
    }
    bf16x8 afr[2], bfr[8];
#pragma unroll
    for (int t = 0; t < 2; t++) {
      int row = wm + t * 16 + col;
      afr[t] = *(const bf16x8*)((const char*)&As[cbuf][0] +
                                (row * 4 + (quad ^ (row & 3))) * 16);
    }
#pragma unroll
    for (int u = 0; u < 8; u++) {
      int row = wn + u * 16 + col;
      bfr[u] = *(const bf16x8*)((const char*)&Bs[cbuf][0] +
                                (row * 4 + (quad ^ (row & 3))) * 16);
    }
#pragma unroll
    for (int t = 0; t < 2; t++)
#pragma unroll
      for (int u = 0; u < 8; u++) acc[t][u] = mfma16(afr[t], bfr[u], acc[t][u]);
    if (it < 7) writeA(nbuf);
  }

#pragma unroll
  for (int u = 0; u < 8; u++) {
    int n = bn + wn + u * 16 + col;
    float bv = bias[n];
#pragma unroll
    for (int t = 0; t < 2; t++)
#pragma unroll
      for (int r = 0; r < 4; r++) {
        int m = bm + wm + t * 16 + quad * 4 + r;
        out[(size_t)m * SRC + n] = acc[t][u][r] + bv;
      }
  }

  if (do_loss) {
#pragma unroll
    for (int off = 32; off; off >>= 1) lacc += __shfl_xor(lacc, off, 64);
    if (lane == 0) lsred[wid] = lacc;
    __syncthreads();
    if (tid == 0) lpart[blockIdx.x] = lsred[0] + lsred[1] + lsred[2] + lsred[3];
  }
}

__global__ __launch_bounds__(256) void k_loss(const float* __restrict__ lpart,
                                              float* __restrict__ outl) {
  float s = 0.f;
  if (threadIdx.x < NBLK_LOSS) s = lpart[threadIdx.x];
#pragma unroll
  for (int off = 32; off; off >>= 1) s += __shfl_xor(s, off, 64);
  __shared__ float ls[4];
  int wv = threadIdx.x >> 6;
  if ((threadIdx.x & 63) == 0) ls[wv] = s;
  __syncthreads();
  if (threadIdx.x == 0) *outl = 1.25f * (ls[0] + ls[1] + ls[2] + ls[3]) / LOSS_DENOM;
}

// ---------------- launch ----------------
extern "C" void kernel_launch(void* const* d_in, const int* in_sizes, int n_in,
                              void* d_out, int out_size, void* d_ws, size_t ws_size,
                              hipStream_t stream) {
  const float* x = (const float*)d_in[0];
  const float* enc_w = (const float*)d_in[1];
  const float* enc_b = (const float*)d_in[2];
  const float* cb = (const float*)d_in[3];
  const float* dec_w = (const float*)d_in[4];
  const float* dec_b = (const float*)d_in[5];
  float* out = (float*)d_out;
  float* out_loss = out + (size_t)N_TOK * SRC;

  char* ws = (char*)d_ws;
  bf16* enc_wT = (bf16*)(ws + 0);           //   524,288 B
  bf16* dec_wT = (bf16*)(ws + 524288);      //   524,288 B
  u8* zb8 = (u8*)(ws + 1048576);            // 2,359,296 B
  u32* cbb8 = (u32*)(ws + 3407872);         // 4,194,304 B
  float* e2s = (float*)(ws + 7602176);      //    65,536 B
  float* pval = (float*)(ws + 7667712);     // 1,179,648 B (9216*32*4)
  int* pidx = (int*)(ws + 8847360);         // 1,179,648 B
  float* lpart = (float*)(ws + 10027008);   //       576 B   (~10 MiB)

  k_prep<<<4224, 256, 0, stream>>>(enc_w, dec_w, cb, enc_wT, dec_wT, cbb8, e2s);
  // encoder: 64x64 tiles, grid 576, barrier-drain-safe A loads
  k_enc<<<dim3(144, 4), 256, 0, stream>>>(x, enc_wT, enc_b, zb8);
  // 512-code slabs: 1536 blocks, 4 resident/CU -> 16 waves/CU of overlap
  k_argmin<<<dim3(NSLAB, 48), 256, 0, stream>>>(zb8, (const u8*)cbb8, e2s, pval, pidx);
  // decoder with fused gather + loss partials: 64x256 tiles, grid 576
  k_dec<<<dim3(144, 4), 256, 0, stream>>>(cb, pval, pidx, zb8, dec_wT, dec_b, out, lpart);
  k_loss<<<1, 256, 0, stream>>>(lpart, out_loss);
}

// Round 6
// 195.958 us; speedup vs baseline: 1.1653x; 1.1653x over previous
//
#include <hip/hip_runtime.h>

typedef __bf16 bf16;
typedef __bf16 bf16x8 __attribute__((ext_vector_type(8)));
typedef float f32x4 __attribute__((ext_vector_type(4)));
typedef int i32x8 __attribute__((ext_vector_type(8)));
typedef unsigned int u32;
typedef unsigned char u8;

#define N_TOK 9216
#define SRC 1024
#define EDIM 256
#define NE 16384
#define NSLAB 32   // 32 slabs of 512 codes
#define SLAB 512
#define NBLK_LOSS 144
#define NEG_CB_SCALE -8192.0f
#define E2_SCALE 4096.0f
#define LOSS_DENOM 2359296.0f  // 16*576*256

__device__ __forceinline__ void async_load16(const void* g, void* l) {
  __builtin_amdgcn_global_load_lds(
      (__attribute__((address_space(1))) void*)(void*)(const_cast<void*>(g)),
      (__attribute__((address_space(3))) void*)l, 16, 0, 0);
}

__device__ __forceinline__ f32x4 mfma16(bf16x8 a, bf16x8 b, f32x4 c) {
  return __builtin_amdgcn_mfma_f32_16x16x32_bf16(a, b, c, 0, 0, 0);
}
// MX-scaled fp8 K=128; scale bytes 0x7F = 2^0 = 1.0; cbsz/blgp 0 = fp8 e4m3
__device__ __forceinline__ f32x4 mfma_mx(i32x8 a, i32x8 b, f32x4 c) {
  return __builtin_amdgcn_mfma_scale_f32_16x16x128_f8f6f4(
      a, b, c, 0, 0, 0, 0x7F7F7F7F, 0, 0x7F7F7F7F);
}

// ---------------- prep: coalesced 64x64 LDS transposes + fp8 codebook -------
// b<64: enc_w [1024,256] -> enc_wT [256,1024]; b<128: dec_w [256,1024] ->
// dec_wT [1024,256]; else codebook (negated fp8, fragment-major swizzle) + e2s.
__global__ __launch_bounds__(256) void k_prep(const float* __restrict__ enc_w,
                                              const float* __restrict__ dec_w,
                                              const float* __restrict__ cb,
                                              bf16* __restrict__ enc_wT,
                                              bf16* __restrict__ dec_wT,
                                              u32* __restrict__ cbb8,
                                              float* __restrict__ e2s) {
  int b = blockIdx.x;
  if (b < 128) {
    __shared__ float T[64][65];
    const float* In;
    bf16* Out;
    int R, C, ti, tj;
    if (b < 64) {  // enc: In 1024x256, tiles 16(k) x 4(n)
      In = enc_w; Out = enc_wT; R = 1024; C = 256;
      ti = b & 15; tj = b >> 4;
    } else {       // dec: In 256x1024, tiles 4(k) x 16(n)
      int t2 = b - 64;
      In = dec_w; Out = dec_wT; R = 256; C = 1024;
      ti = t2 & 3; tj = t2 >> 2;
    }
    int c0 = threadIdx.x & 63, r0 = threadIdx.x >> 6;
#pragma unroll
    for (int i = 0; i < 16; i++) {
      int rr = r0 + i * 4;
      T[rr][c0] = In[(size_t)(ti * 64 + rr) * C + tj * 64 + c0];
    }
    __syncthreads();
#pragma unroll
    for (int i = 0; i < 16; i++) {
      int rr = r0 + i * 4;
      Out[(size_t)(tj * 64 + rr) * R + ti * 64 + c0] = (bf16)T[c0][rr];
    }
  } else {
    // codebook row r: stored slot s holds source granule h=(s&8)|((s&7)^(r&7)),
    // scaled by -8192 (negated -> distance epilogue is the MFMA acc itself).
    int row = (b - 128) * 4 + (threadIdx.x >> 6);
    int lane = threadIdx.x & 63;
    int slot = lane >> 2;
    int h = (slot & 8) | ((slot & 7) ^ (row & 7));
    int k0 = h * 16 + (lane & 3) * 4;
    float4 v = *(const float4*)(cb + (size_t)row * EDIM + k0);
    int pk = __builtin_amdgcn_cvt_pk_fp8_f32(v.x * NEG_CB_SCALE, v.y * NEG_CB_SCALE, 0, false);
    pk = __builtin_amdgcn_cvt_pk_fp8_f32(v.z * NEG_CB_SCALE, v.w * NEG_CB_SCALE, pk, true);
    cbb8[(size_t)row * 64 + lane] = (u32)pk;
    float sq = v.x * v.x + v.y * v.y + v.z * v.z + v.w * v.w;
#pragma unroll
    for (int off = 32; off; off >>= 1) sq += __shfl_xor(sq, off, 64);
    if (lane == 0) e2s[row] = E2_SCALE * (sq + 1.0f);
  }
}

// ---------------- encoder GEMM: 64x64 tile, fused f32->bf16, fp8 out --------
// z = x @ enc_wT^T + enc_b. grid (144,4). 4 waves 2x2, wave tile 32x32.
// f32 A-loads issued AFTER the barrier so barriers drain only old async loads.
__global__ __launch_bounds__(256) void k_enc(const float* __restrict__ x,
                                             const bf16* __restrict__ wT,
                                             const float* __restrict__ bias,
                                             u8* __restrict__ z8) {
  __shared__ __align__(16) bf16 As[2][64 * 32];
  __shared__ __align__(16) bf16 Bs[2][64 * 32];
  const int tid = threadIdx.x;
  const int wid = tid >> 6, lane = tid & 63;
  const int col = lane & 15, quad = lane >> 4;
  const int wm = (wid >> 1) * 32, wn = (wid & 1) * 32;
  const int bm = blockIdx.x * 64, bn = blockIdx.y * 64;
  f32x4 acc[2][2] = {};
  const int arow = tid >> 2, ags = tid & 3;

  float4 q0, q1;
  auto loadA = [&](int kc) {
    const float* p = x + (size_t)(bm + arow) * SRC + kc + ags * 8;
    q0 = *(const float4*)p;
    q1 = *(const float4*)(p + 4);
  };
  auto writeA = [&](int bb) {
    bf16x8 o = {(bf16)q0.x, (bf16)q0.y, (bf16)q0.z, (bf16)q0.w,
                (bf16)q1.x, (bf16)q1.y, (bf16)q1.z, (bf16)q1.w};
    *(bf16x8*)((char*)&As[bb][0] + (arow * 4 + (ags ^ (arow & 3))) * 16) = o;
  };
  auto stageB = [&](int kc, int bb) {
    int row = tid >> 2;
    int gg = (tid & 3) ^ (row & 3);
    async_load16(wT + (size_t)(bn + row) * SRC + kc + gg * 8,
                 (char*)&Bs[bb][0] + wid * 1024);
  };

  loadA(0);
  writeA(0);
  stageB(0, 0);
  for (int it = 0; it < 32; it++) {
    int cbuf = it & 1, nbuf = cbuf ^ 1;
    __syncthreads();
    if (it < 31) {
      loadA((it + 1) * 32);
      stageB((it + 1) * 32, nbuf);
    }
    bf16x8 afr[2], bfr[2];
#pragma unroll
    for (int t = 0; t < 2; t++) {
      int row = wm + t * 16 + col;
      afr[t] = *(const bf16x8*)((const char*)&As[cbuf][0] +
                                (row * 4 + (quad ^ (row & 3))) * 16);
    }
#pragma unroll
    for (int u = 0; u < 2; u++) {
      int row = wn + u * 16 + col;
      bfr[u] = *(const bf16x8*)((const char*)&Bs[cbuf][0] +
                                (row * 4 + (quad ^ (row & 3))) * 16);
    }
#pragma unroll
    for (int t = 0; t < 2; t++)
#pragma unroll
      for (int u = 0; u < 2; u++) acc[t][u] = mfma16(afr[t], bfr[u], acc[t][u]);
    if (it < 31) writeA(nbuf);
  }
#pragma unroll
  for (int u = 0; u < 2; u++) {
    int n = bn + wn + u * 16 + col;
    float bv = bias[n];
#pragma unroll
    for (int t = 0; t < 2; t++)
#pragma unroll
      for (int r = 0; r < 4; r++) {
        int m = bm + wm + t * 16 + quad * 4 + r;
        float v = acc[t][u][r] + bv;
        int pk = __builtin_amdgcn_cvt_pk_fp8_f32(v, v, 0, false);
        z8[(size_t)m * EDIM + n] = (u8)(pk & 0xFF);
      }
  }
}

// ---------------- fused MX-fp8 cross-GEMM + argmin v13 ----------------
// v13 = v12 slab split with the correct launch bounds. Empirical hipcc VGPR
// cap for 256-thread blocks is ~256/arg: arg 4 capped at 64 and spilled
// af[3][2] (R5: 97 MB scratch writes). arg 3 caps at ~84; kernel needs ~80
// (v8-proven). Hardware residency is then min(LDS: floor(160/34)=4,
// VGPR: 80<=128 -> 4 waves/SIMD) = 4 blocks/CU -- the occupancy target --
// without any allocator pressure. grid (32 slabs, 48 token-blocks) = 1536.
__global__ __launch_bounds__(256, 3) void k_argmin(const u8* __restrict__ zb8,
                                                   const u8* __restrict__ cbb8,
                                                   const float* __restrict__ e2s,
                                                   float* __restrict__ pval,
                                                   int* __restrict__ pidx) {
  __shared__ __align__(16) u8 Cs[2 * 16384];
  __shared__ __align__(16) float Es[SLAB];
  const int tid = threadIdx.x;
  const int wid = tid >> 6, lane = tid & 63;
  const int col = lane & 15, quad = lane >> 4;
  const int g = blockIdx.x;  // slab id [0,32)
  const int tw = blockIdx.y * 192 + wid * 48;

  // e2s for this slab -> LDS (2 KB: waves 0,1 only)
  if (wid < 2)
    async_load16((const u8*)(e2s + g * SLAB) + (size_t)tid * 16,
                 (char*)Es + wid * 1024);

  i32x8 af[3][2];
#pragma unroll
  for (int t = 0; t < 3; t++)
#pragma unroll
    for (int m = 0; m < 2; m++) {
      const u8* p = zb8 + (size_t)(tw + t * 16 + col) * EDIM + m * 128 + quad * 32;
      int4 lo = *(const int4*)p;
      int4 hi = *(const int4*)(p + 16);
      af[t][m] = (i32x8){lo.x, lo.y, lo.z, lo.w, hi.x, hi.y, hi.z, hi.w};
    }

  u32 best[3][4];
#pragma unroll
  for (int t = 0; t < 3; t++)
#pragma unroll
    for (int r = 0; r < 4; r++) best[t][r] = 0xFFFFFFFFu;

  auto stage_load = [&](int st, int bb) {
    const u8* src = cbb8 + (size_t)(g * SLAB + st * 64) * EDIM;
#pragma unroll
    for (int j = 0; j < 4; j++) {
      async_load16(src + (wid * 256 + j * 64 + lane) * 16,
                   (char*)Cs + bb * 16384 + wid * 4096 + j * 1024);
    }
  };

  stage_load(0, 0);
  asm volatile("s_waitcnt vmcnt(0)" ::: "memory");
  __builtin_amdgcn_s_barrier();

  const int r7 = col & 7;
  const int s0 = ((2 * quad) ^ r7) * 16;
  const int s1 = ((2 * quad + 1) ^ r7) * 16;

  for (int st = 0; st < 8; st++) {
    const char* bbase = (const char*)Cs + (st & 1) * 16384;
#pragma unroll
    for (int u = 0; u < 4; u++) {
      // ---- phase u: LDS reads for this quadrant (issued before the barrier,
      // completed by the lgkmcnt(0) after it -> latency spans the barrier)
      const int rb = (u * 16 + col) * 256;
      int4 a0 = *(const int4*)(bbase + rb + s0);
      int4 a1 = *(const int4*)(bbase + rb + s1);
      int4 b0 = *(const int4*)(bbase + rb + 128 + s0);
      int4 b1 = *(const int4*)(bbase + rb + 128 + s1);
      float ev = Es[st * 64 + u * 16 + col];
      // prefetch next stage: phase 1 only (phase-0 barrier proves all waves
      // finished reading this buffer in stage st-1)
      if (u == 1 && st < 7) stage_load(st + 1, (st & 1) ^ 1);
      __builtin_amdgcn_s_barrier();
      asm volatile("s_waitcnt lgkmcnt(0)" ::: "memory");
      __builtin_amdgcn_sched_barrier(0);
      __builtin_amdgcn_s_setprio(1);
      i32x8 bm0 = (i32x8){a0.x, a0.y, a0.z, a0.w, a1.x, a1.y, a1.z, a1.w};
      i32x8 bm1 = (i32x8){b0.x, b0.y, b0.z, b0.w, b1.x, b1.y, b1.z, b1.w};
      f32x4 c0 = (f32x4){ev, ev, ev, ev};
      f32x4 c1 = c0, c2 = c0;
      c0 = mfma_mx(af[0][0], bm0, c0);
      c1 = mfma_mx(af[1][0], bm0, c1);
      c2 = mfma_mx(af[2][0], bm0, c2);
      c0 = mfma_mx(af[0][1], bm1, c0);
      c1 = mfma_mx(af[1][1], bm1, c1);
      c2 = mfma_mx(af[2][1], bm1, c2);
      __builtin_amdgcn_s_setprio(0);
      // per-phase epilogue: one key per (t,r) this quadrant; overlaps next
      // phase's ds_reads
      const u32 code = (u32)(st * 4 + u);  // [0,32): fits the 6-bit field
#pragma unroll
      for (int r = 0; r < 4; r++) {
        u32 k0 = (__float_as_uint(c0[r]) & 0xFFFFFFC0u) | code;
        u32 k1 = (__float_as_uint(c1[r]) & 0xFFFFFFC0u) | code;
        u32 k2 = (__float_as_uint(c2[r]) & 0xFFFFFFC0u) | code;
        best[0][r] = k0 < best[0][r] ? k0 : best[0][r];
        best[1][r] = k1 < best[1][r] ? k1 : best[1][r];
        best[2][r] = k2 < best[2][r] ? k2 : best[2][r];
      }
    }
    // drain own prefetch (issued 3 phases ago), then end-of-stage barrier:
    // after it, ALL waves' loads for st+1 have landed.
    if (st < 7) asm volatile("s_waitcnt vmcnt(0)" ::: "memory");
    __builtin_amdgcn_s_barrier();
  }

#pragma unroll
  for (int t = 0; t < 3; t++)
#pragma unroll
    for (int r = 0; r < 4; r++) {
      u32 key = best[t][r];
      int cw = col;
#pragma unroll
      for (int off = 1; off < 16; off <<= 1) {
        u32 ok = (u32)__shfl_xor((int)key, off, 64);
        int oc = __shfl_xor(cw, off, 64);
        if (ok < key) { key = ok; cw = oc; }
      }
      if (col == 0) {
        int token = tw + t * 16 + quad * 4 + r;
        pval[token * NSLAB + g] = __uint_as_float(key & 0xFFFFFFC0u);
        pidx[token * NSLAB + g] = g * SLAB + (int)(key & 63u) * 16 + cw;
      }
    }
}

// ---------------- decoder GEMM with fused gather + loss ----------------
// out = cb[idx] @ dec_wT^T + dec_b. grid (144,4), 64 tokens x 256 cols.
// Phase 0: per-token argmin combine (4 lanes/token, 8 slabs each). Phase 1:
// K-loop; A-side gathers cb rows f32 (LLC) -> bf16 -> LDS.
// by==0 blocks also accumulate the loss partial (vs fp8 z).
__global__ __launch_bounds__(256) void k_dec(const float* __restrict__ cb,
                                             const float* __restrict__ pval,
                                             const int* __restrict__ pidx,
                                             const u8* __restrict__ zb8,
                                             const bf16* __restrict__ wT,
                                             const float* __restrict__ bias,
                                             float* __restrict__ out,
                                             float* __restrict__ lpart) {
  __shared__ __align__(16) bf16 As[2][64 * 32];
  __shared__ __align__(16) bf16 Bs[2][256 * 32];
  __shared__ int idxL[64];
  __shared__ float lsred[4];
  const int tid = threadIdx.x;
  const int wid = tid >> 6, lane = tid & 63;
  const int col = lane & 15, quad = lane >> 4;
  const int wm = (wid >> 1) * 32, wn = (wid & 1) * 128;
  const int bm = blockIdx.x * 64, bn = blockIdx.y * 256;
  const bool do_loss = (blockIdx.y == 0);

  // ---- phase 0: combine the 32 slab candidates for this block's 64 tokens
  {
    int tl = tid >> 2, j0 = tid & 3;
    float v = 3.4e38f;
    int idx = 0;
#pragma unroll
    for (int jj = 0; jj < 8; jj++) {
      int grp = j0 * 8 + jj;
      float ov = pval[(bm + tl) * NSLAB + grp];
      int oi = pidx[(bm + tl) * NSLAB + grp];
      if (ov < v || (ov == v && oi < idx)) { v = ov; idx = oi; }
    }
#pragma unroll
    for (int off = 1; off < 4; off <<= 1) {
      float ov = __shfl_xor(v, off, 64);
      int oi = __shfl_xor(idx, off, 64);
      if (ov < v || (ov == v && oi < idx)) { v = ov; idx = oi; }
    }
    if (j0 == 0) idxL[tl] = idx;
  }
  __syncthreads();

  const int arow = tid >> 2, ags = tid & 3;
  const int ridx = idxL[arow];
  float lacc = 0.f;
  f32x4 acc[2][8] = {};

  float4 q0, q1;
  auto loadA = [&](int kc) {
    const float* p = cb + (size_t)ridx * EDIM + kc + ags * 8;
    q0 = *(const float4*)p;
    q1 = *(const float4*)(p + 4);
    if (do_loss) {
      u32 zw0 = *(const u32*)(zb8 + (size_t)(bm + arow) * EDIM + kc + ags * 8);
      u32 zw1 = *(const u32*)(zb8 + (size_t)(bm + arow) * EDIM + kc + ags * 8 + 4);
      float d0 = q0.x - __builtin_amdgcn_cvt_f32_fp8(zw0, 0);
      float d1 = q0.y - __builtin_amdgcn_cvt_f32_fp8(zw0, 1);
      float d2 = q0.z - __builtin_amdgcn_cvt_f32_fp8(zw0, 2);
      float d3 = q0.w - __builtin_amdgcn_cvt_f32_fp8(zw0, 3);
      float d4 = q1.x - __builtin_amdgcn_cvt_f32_fp8(zw1, 0);
      float d5 = q1.y - __builtin_amdgcn_cvt_f32_fp8(zw1, 1);
      float d6 = q1.z - __builtin_amdgcn_cvt_f32_fp8(zw1, 2);
      float d7 = q1.w - __builtin_amdgcn_cvt_f32_fp8(zw1, 3);
      lacc += d0 * d0 + d1 * d1 + d2 * d2 + d3 * d3 +
              d4 * d4 + d5 * d5 + d6 * d6 + d7 * d7;
    }
  };
  auto writeA = [&](int bb) {
    bf16x8 o = {(bf16)q0.x, (bf16)q0.y, (bf16)q0.z, (bf16)q0.w,
                (bf16)q1.x, (bf16)q1.y, (bf16)q1.z, (bf16)q1.w};
    *(bf16x8*)((char*)&As[bb][0] + (arow * 4 + (ags ^ (arow & 3))) * 16) = o;
  };
  auto stageB = [&](int kc, int bb) {
#pragma unroll
    for (int j = 0; j < 4; j++) {
      int slot = wid * 256 + j * 64 + lane;
      int row = slot >> 2;
      int gg = (slot & 3) ^ (row & 3);
      async_load16(wT + (size_t)(bn + row) * EDIM + kc + gg * 8,
                   (char*)&Bs[bb][0] + wid * 4096 + j * 1024);
    }
  };

  loadA(0);
  writeA(0);
  stageB(0, 0);
  for (int it = 0; it < 8; it++) {
    int cbuf = it & 1, nbuf = cbuf ^ 1;
    __syncthreads();
    if (it < 7) {
      loadA((it + 1) * 32);
      stageB((it + 1) * 32, nbuf);
    }
    bf16x8 afr[2], bfr[8];
#pragma unroll
    for (int t = 0; t < 2; t++) {
      int row = wm + t * 16 + col;
      afr[t] = *(const bf16x8*)((const char*)&As[cbuf][0] +
                                (row * 4 + (quad ^ (row & 3))) * 16);
    }
#pragma unroll
    for (int u = 0; u < 8; u++) {
      int row = wn + u * 16 + col;
      bfr[u] = *(const bf16x8*)((const char*)&Bs[cbuf][0] +
                                (row * 4 + (quad ^ (row & 3))) * 16);
    }
#pragma unroll
    for (int t = 0; t < 2; t++)
#pragma unroll
      for (int u = 0; u < 8; u++) acc[t][u] = mfma16(afr[t], bfr[u], acc[t][u]);
    if (it < 7) writeA(nbuf);
  }

#pragma unroll
  for (int u = 0; u < 8; u++) {
    int n = bn + wn + u * 16 + col;
    float bv = bias[n];
#pragma unroll
    for (int t = 0; t < 2; t++)
#pragma unroll
      for (int r = 0; r < 4; r++) {
        int m = bm + wm + t * 16 + quad * 4 + r;
        out[(size_t)m * SRC + n] = acc[t][u][r] + bv;
      }
  }

  if (do_loss) {
#pragma unroll
    for (int off = 32; off; off >>= 1) lacc += __shfl_xor(lacc, off, 64);
    if (lane == 0) lsred[wid] = lacc;
    __syncthreads();
    if (tid == 0) lpart[blockIdx.x] = lsred[0] + lsred[1] + lsred[2] + lsred[3];
  }
}

__global__ __launch_bounds__(256) void k_loss(const float* __restrict__ lpart,
                                              float* __restrict__ outl) {
  float s = 0.f;
  if (threadIdx.x < NBLK_LOSS) s = lpart[threadIdx.x];
#pragma unroll
  for (int off = 32; off; off >>= 1) s += __shfl_xor(s, off, 64);
  __shared__ float ls[4];
  int wv = threadIdx.x >> 6;
  if ((threadIdx.x & 63) == 0) ls[wv] = s;
  __syncthreads();
  if (threadIdx.x == 0) *outl = 1.25f * (ls[0] + ls[1] + ls[2] + ls[3]) / LOSS_DENOM;
}

// ---------------- launch ----------------
extern "C" void kernel_launch(void* const* d_in, const int* in_sizes, int n_in,
                              void* d_out, int out_size, void* d_ws, size_t ws_size,
                              hipStream_t stream) {
  const float* x = (const float*)d_in[0];
  const float* enc_w = (const float*)d_in[1];
  const float* enc_b = (const float*)d_in[2];
  const float* cb = (const float*)d_in[3];
  const float* dec_w = (const float*)d_in[4];
  const float* dec_b = (const float*)d_in[5];
  float* out = (float*)d_out;
  float* out_loss = out + (size_t)N_TOK * SRC;

  char* ws = (char*)d_ws;
  bf16* enc_wT = (bf16*)(ws + 0);           //   524,288 B
  bf16* dec_wT = (bf16*)(ws + 524288);      //   524,288 B
  u8* zb8 = (u8*)(ws + 1048576);            // 2,359,296 B
  u32* cbb8 = (u32*)(ws + 3407872);         // 4,194,304 B
  float* e2s = (float*)(ws + 7602176);      //    65,536 B
  float* pval = (float*)(ws + 7667712);     // 1,179,648 B (9216*32*4)
  int* pidx = (int*)(ws + 8847360);         // 1,179,648 B
  float* lpart = (float*)(ws + 10027008);   //       576 B   (~10 MiB)

  k_prep<<<4224, 256, 0, stream>>>(enc_w, dec_w, cb, enc_wT, dec_wT, cbb8, e2s);
  // encoder: 64x64 tiles, grid 576, barrier-drain-safe A loads
  k_enc<<<dim3(144, 4), 256, 0, stream>>>(x, enc_wT, enc_b, zb8);
  // 512-code slabs: 1536 blocks, 4 resident/CU (LDS-limited), no VGPR cap hit
  k_argmin<<<dim3(NSLAB, 48), 256, 0, stream>>>(zb8, (const u8*)cbb8, e2s, pval, pidx);
  // decoder with fused gather + loss partials: 64x256 tiles, grid 576
  k_dec<<<dim3(144, 4), 256, 0, stream>>>(cb, pval, pidx, zb8, dec_wT, dec_b, out, lpart);
  k_loss<<<1, 256, 0, stream>>>(lpart, out_loss);
}

// Round 7
// 180.259 us; speedup vs baseline: 1.2667x; 1.0871x over previous
//
#include <hip/hip_runtime.h>

typedef __bf16 bf16;
typedef __bf16 bf16x8 __attribute__((ext_vector_type(8)));
typedef float f32x4 __attribute__((ext_vector_type(4)));
typedef int i32x8 __attribute__((ext_vector_type(8)));
typedef unsigned int u32;
typedef unsigned char u8;

#define N_TOK 9216
#define SRC 1024
#define EDIM 256
#define NE 16384
#define GROUPS 16
#define GSIZE 1024
#define NEG_CB_SCALE -8192.0f
#define E2_SCALE 4096.0f
#define LOSS_DENOM 2359296.0f  // 16*576*256

__device__ __forceinline__ void async_load16(const void* g, void* l) {
  __builtin_amdgcn_global_load_lds(
      (__attribute__((address_space(1))) void*)(void*)(const_cast<void*>(g)),
      (__attribute__((address_space(3))) void*)l, 16, 0, 0);
}

__device__ __forceinline__ f32x4 mfma16(bf16x8 a, bf16x8 b, f32x4 c) {
  return __builtin_amdgcn_mfma_f32_16x16x32_bf16(a, b, c, 0, 0, 0);
}
// MX-scaled fp8 K=128; scale bytes 0x7F = 2^0 = 1.0; cbsz/blgp 0 = fp8 e4m3
__device__ __forceinline__ f32x4 mfma_mx(i32x8 a, i32x8 b, f32x4 c) {
  return __builtin_amdgcn_mfma_scale_f32_16x16x128_f8f6f4(
      a, b, c, 0, 0, 0, 0x7F7F7F7F, 0, 0x7F7F7F7F);
}

// ---------------- prep: coalesced 64x64 LDS transposes + fp8 codebook -------
// b<64: enc_w [1024,256] -> enc_wT [256,1024]; b<128: dec_w [256,1024] ->
// dec_wT [1024,256]; else codebook (negated fp8, fragment-major swizzle) + e2s.
// Block 0 also zeroes out_loss (k_dec atomicAdds into it; k_loss eliminated).
__global__ __launch_bounds__(256) void k_prep(const float* __restrict__ enc_w,
                                              const float* __restrict__ dec_w,
                                              const float* __restrict__ cb,
                                              bf16* __restrict__ enc_wT,
                                              bf16* __restrict__ dec_wT,
                                              u32* __restrict__ cbb8,
                                              float* __restrict__ e2s,
                                              float* __restrict__ outl) {
  int b = blockIdx.x;
  if (b == 0 && threadIdx.x == 0) *outl = 0.f;
  if (b < 128) {
    __shared__ float T[64][65];
    const float* In;
    bf16* Out;
    int R, C, ti, tj;
    if (b < 64) {  // enc: In 1024x256, tiles 16(k) x 4(n)
      In = enc_w; Out = enc_wT; R = 1024; C = 256;
      ti = b & 15; tj = b >> 4;
    } else {       // dec: In 256x1024, tiles 4(k) x 16(n)
      int t2 = b - 64;
      In = dec_w; Out = dec_wT; R = 256; C = 1024;
      ti = t2 & 3; tj = t2 >> 2;
    }
    int c0 = threadIdx.x & 63, r0 = threadIdx.x >> 6;
#pragma unroll
    for (int i = 0; i < 16; i++) {
      int rr = r0 + i * 4;
      T[rr][c0] = In[(size_t)(ti * 64 + rr) * C + tj * 64 + c0];
    }
    __syncthreads();
#pragma unroll
    for (int i = 0; i < 16; i++) {
      int rr = r0 + i * 4;
      Out[(size_t)(tj * 64 + rr) * R + ti * 64 + c0] = (bf16)T[c0][rr];
    }
  } else {
    // codebook row r: stored slot s holds source granule h=(s&8)|((s&7)^(r&7)),
    // scaled by -8192 (negated -> distance epilogue is the MFMA acc itself).
    int row = (b - 128) * 4 + (threadIdx.x >> 6);
    int lane = threadIdx.x & 63;
    int slot = lane >> 2;
    int h = (slot & 8) | ((slot & 7) ^ (row & 7));
    int k0 = h * 16 + (lane & 3) * 4;
    float4 v = *(const float4*)(cb + (size_t)row * EDIM + k0);
    int pk = __builtin_amdgcn_cvt_pk_fp8_f32(v.x * NEG_CB_SCALE, v.y * NEG_CB_SCALE, 0, false);
    pk = __builtin_amdgcn_cvt_pk_fp8_f32(v.z * NEG_CB_SCALE, v.w * NEG_CB_SCALE, pk, true);
    cbb8[(size_t)row * 64 + lane] = (u32)pk;
    float sq = v.x * v.x + v.y * v.y + v.z * v.z + v.w * v.w;
#pragma unroll
    for (int off = 32; off; off >>= 1) sq += __shfl_xor(sq, off, 64);
    if (lane == 0) e2s[row] = E2_SCALE * (sq + 1.0f);
  }
}

// ---------------- encoder GEMM v2: 64x64 tile, BK=64, fp8 out --------------
// z = x @ enc_wT^T + enc_b. grid (144,4). 4 waves 2x2, wave tile 32x32.
// BK=64 -> 16 K-iterations (was 32): half the barrier+drain count at equal
// MFMA/LDS/HBM totals. Per-accumulator K-order identical to BK=32 (kk=0 then
// kk=1 covers the same ascending 32-k windows) -> bit-identical z.
// LDS granule layout: row-major [64][8 granules of 8 bf16], granule slot
// g stored at g^(row&7) (XOR swizzle, conflict-even reads).
__global__ __launch_bounds__(256) void k_enc(const float* __restrict__ x,
                                             const bf16* __restrict__ wT,
                                             const float* __restrict__ bias,
                                             u8* __restrict__ z8) {
  __shared__ __align__(16) bf16 As[2][64 * 64];
  __shared__ __align__(16) bf16 Bs[2][64 * 64];
  const int tid = threadIdx.x;
  const int wid = tid >> 6, lane = tid & 63;
  const int col = lane & 15, quad = lane >> 4;
  const int wm = (wid >> 1) * 32, wn = (wid & 1) * 32;
  const int bm = blockIdx.x * 64, bn = blockIdx.y * 64;
  f32x4 acc[2][2] = {};
  const int arow = tid >> 2, ags = tid & 3;  // 4 threads/row, 16 floats each

  float4 q0, q1, q2, q3;
  auto loadA = [&](int kc) {
    const float* p = x + (size_t)(bm + arow) * SRC + kc + ags * 16;
    q0 = *(const float4*)p;
    q1 = *(const float4*)(p + 4);
    q2 = *(const float4*)(p + 8);
    q3 = *(const float4*)(p + 12);
  };
  auto writeA = [&](int bb) {
    bf16x8 o0 = {(bf16)q0.x, (bf16)q0.y, (bf16)q0.z, (bf16)q0.w,
                 (bf16)q1.x, (bf16)q1.y, (bf16)q1.z, (bf16)q1.w};
    bf16x8 o1 = {(bf16)q2.x, (bf16)q2.y, (bf16)q2.z, (bf16)q2.w,
                 (bf16)q3.x, (bf16)q3.y, (bf16)q3.z, (bf16)q3.w};
    int g0 = 2 * ags, g1 = 2 * ags + 1;
    *(bf16x8*)((char*)&As[bb][0] + (arow * 8 + (g0 ^ (arow & 7))) * 16) = o0;
    *(bf16x8*)((char*)&As[bb][0] + (arow * 8 + (g1 ^ (arow & 7))) * 16) = o1;
  };
  auto stageB = [&](int kc, int bb) {
    // 8 KB: 512 slots of 16B; slot = j*256+tid; row = slot>>3, granule
    // stored at slot&7 sources granule (slot&7)^(row&7).
#pragma unroll
    for (int j = 0; j < 2; j++) {
      int slot = j * 256 + tid;
      int row = slot >> 3;
      int g = (slot & 7) ^ (row & 7);
      async_load16(wT + (size_t)(bn + row) * SRC + kc + g * 8,
                   (char*)&Bs[bb][0] + j * 4096 + wid * 1024);
    }
  };

  loadA(0);
  writeA(0);
  stageB(0, 0);
  for (int it = 0; it < 16; it++) {
    int cbuf = it & 1, nbuf = cbuf ^ 1;
    __syncthreads();
    if (it < 15) {
      loadA((it + 1) * 64);
      stageB((it + 1) * 64, nbuf);
    }
    bf16x8 afr[2][2], bfr[2][2];
#pragma unroll
    for (int t = 0; t < 2; t++) {
      int row = wm + t * 16 + col;
#pragma unroll
      for (int kk = 0; kk < 2; kk++)
        afr[t][kk] = *(const bf16x8*)((const char*)&As[cbuf][0] +
                                      (row * 8 + ((kk * 4 + quad) ^ (row & 7))) * 16);
    }
#pragma unroll
    for (int u = 0; u < 2; u++) {
      int row = wn + u * 16 + col;
#pragma unroll
      for (int kk = 0; kk < 2; kk++)
        bfr[u][kk] = *(const bf16x8*)((const char*)&Bs[cbuf][0] +
                                      (row * 8 + ((kk * 4 + quad) ^ (row & 7))) * 16);
    }
#pragma unroll
    for (int kk = 0; kk < 2; kk++)
#pragma unroll
      for (int t = 0; t < 2; t++)
#pragma unroll
        for (int u = 0; u < 2; u++)
          acc[t][u] = mfma16(afr[t][kk], bfr[u][kk], acc[t][u]);
    if (it < 15) writeA(nbuf);
  }
#pragma unroll
  for (int u = 0; u < 2; u++) {
    int n = bn + wn + u * 16 + col;
    float bv = bias[n];
#pragma unroll
    for (int t = 0; t < 2; t++)
#pragma unroll
      for (int r = 0; r < 4; r++) {
        int m = bm + wm + t * 16 + quad * 4 + r;
        float v = acc[t][u][r] + bv;
        int pk = __builtin_amdgcn_cvt_pk_fp8_f32(v, v, 0, false);
        z8[(size_t)m * EDIM + n] = (u8)(pk & 0xFF);
      }
  }
}

// ---------------- fused MX-fp8 cross-GEMM + argmin (v8, measured 42.2us) ----
// 4-phase schedule per 64-code stage: {4x ds_read_b128 + e2 read -> barrier ->
// lgkmcnt(0) -> setprio(1) -> 6 MFMA -> setprio(0) -> per-phase key/min}.
// Prefetch in phase 1; single per-wave vmcnt(0) before the end-of-stage
// barrier. Reverted verbatim after v9-v13 structural variants all regressed.
__global__ __launch_bounds__(256, 3) void k_argmin(const u8* __restrict__ zb8,
                                                   const u8* __restrict__ cbb8,
                                                   const float* __restrict__ e2s,
                                                   float* __restrict__ pval,
                                                   int* __restrict__ pidx) {
  __shared__ __align__(16) u8 Cs[2 * 16384];
  __shared__ __align__(16) float Es[1024];
  const int tid = threadIdx.x;
  const int wid = tid >> 6, lane = tid & 63;
  const int col = lane & 15, quad = lane >> 4;
  const int g = blockIdx.y;
  const int tw = blockIdx.x * 192 + wid * 48;

  // e2s for this group -> LDS (one async instr per thread)
  async_load16((const u8*)(e2s + g * GSIZE) + (size_t)tid * 16,
               (char*)Es + wid * 1024);

  i32x8 af[3][2];
#pragma unroll
  for (int t = 0; t < 3; t++)
#pragma unroll
    for (int m = 0; m < 2; m++) {
      const u8* p = zb8 + (size_t)(tw + t * 16 + col) * EDIM + m * 128 + quad * 32;
      int4 lo = *(const int4*)p;
      int4 hi = *(const int4*)(p + 16);
      af[t][m] = (i32x8){lo.x, lo.y, lo.z, lo.w, hi.x, hi.y, hi.z, hi.w};
    }

  u32 best[3][4];
#pragma unroll
  for (int t = 0; t < 3; t++)
#pragma unroll
    for (int r = 0; r < 4; r++) best[t][r] = 0xFFFFFFFFu;

  auto stage_load = [&](int st, int bb) {
    const u8* src = cbb8 + (size_t)(g * GSIZE + st * 64) * EDIM;
#pragma unroll
    for (int j = 0; j < 4; j++) {
      async_load16(src + (wid * 256 + j * 64 + lane) * 16,
                   (char*)Cs + bb * 16384 + wid * 4096 + j * 1024);
    }
  };

  stage_load(0, 0);
  asm volatile("s_waitcnt vmcnt(0)" ::: "memory");
  __builtin_amdgcn_s_barrier();

  const int r7 = col & 7;
  const int s0 = ((2 * quad) ^ r7) * 16;
  const int s1 = ((2 * quad + 1) ^ r7) * 16;

  for (int st = 0; st < 16; st++) {
    const char* bbase = (const char*)Cs + (st & 1) * 16384;
#pragma unroll
    for (int u = 0; u < 4; u++) {
      const int rb = (u * 16 + col) * 256;
      int4 a0 = *(const int4*)(bbase + rb + s0);
      int4 a1 = *(const int4*)(bbase + rb + s1);
      int4 b0 = *(const int4*)(bbase + rb + 128 + s0);
      int4 b1 = *(const int4*)(bbase + rb + 128 + s1);
      float ev = Es[st * 64 + u * 16 + col];
      if (u == 1 && st < 15) stage_load(st + 1, (st & 1) ^ 1);
      __builtin_amdgcn_s_barrier();
      asm volatile("s_waitcnt lgkmcnt(0)" ::: "memory");
      __builtin_amdgcn_sched_barrier(0);
      __builtin_amdgcn_s_setprio(1);
      i32x8 bm0 = (i32x8){a0.x, a0.y, a0.z, a0.w, a1.x, a1.y, a1.z, a1.w};
      i32x8 bm1 = (i32x8){b0.x, b0.y, b0.z, b0.w, b1.x, b1.y, b1.z, b1.w};
      f32x4 c0 = (f32x4){ev, ev, ev, ev};
      f32x4 c1 = c0, c2 = c0;
      c0 = mfma_mx(af[0][0], bm0, c0);
      c1 = mfma_mx(af[1][0], bm0, c1);
      c2 = mfma_mx(af[2][0], bm0, c2);
      c0 = mfma_mx(af[0][1], bm1, c0);
      c1 = mfma_mx(af[1][1], bm1, c1);
      c2 = mfma_mx(af[2][1], bm1, c2);
      __builtin_amdgcn_s_setprio(0);
      const u32 code = (u32)(st * 4 + u);
#pragma unroll
      for (int r = 0; r < 4; r++) {
        u32 k0 = (__float_as_uint(c0[r]) & 0xFFFFFFC0u) | code;
        u32 k1 = (__float_as_uint(c1[r]) & 0xFFFFFFC0u) | code;
        u32 k2 = (__float_as_uint(c2[r]) & 0xFFFFFFC0u) | code;
        best[0][r] = k0 < best[0][r] ? k0 : best[0][r];
        best[1][r] = k1 < best[1][r] ? k1 : best[1][r];
        best[2][r] = k2 < best[2][r] ? k2 : best[2][r];
      }
    }
    if (st < 15) asm volatile("s_waitcnt vmcnt(0)" ::: "memory");
    __builtin_amdgcn_s_barrier();
  }

#pragma unroll
  for (int t = 0; t < 3; t++)
#pragma unroll
    for (int r = 0; r < 4; r++) {
      u32 key = best[t][r];
      int cw = col;
#pragma unroll
      for (int off = 1; off < 16; off <<= 1) {
        u32 ok = (u32)__shfl_xor((int)key, off, 64);
        int oc = __shfl_xor(cw, off, 64);
        if (ok < key) { key = ok; cw = oc; }
      }
      if (col == 0) {
        int token = tw + t * 16 + quad * 4 + r;
        pval[token * GROUPS + g] = __uint_as_float(key & 0xFFFFFFC0u);
        pidx[token * GROUPS + g] = g * GSIZE + (int)(key & 63u) * 16 + cw;
      }
    }
}

// ---------------- decoder GEMM with fused gather + loss ----------------
// out = cb[idx] @ dec_wT^T + dec_b. grid (144,4), 64 tokens x 256 cols.
// Phase 0: per-token argmin combine (4 lanes/token). Phase 1: K-loop; A-side
// gathers cb rows f32 (LLC) -> bf16 -> LDS; zqb never materialized.
// by==0 blocks accumulate the loss partial and atomicAdd the scaled result
// straight into out_loss (k_loss kernel eliminated; prep zeroes out_loss).
__global__ __launch_bounds__(256) void k_dec(const float* __restrict__ cb,
                                             const float* __restrict__ pval,
                                             const int* __restrict__ pidx,
                                             const u8* __restrict__ zb8,
                                             const bf16* __restrict__ wT,
                                             const float* __restrict__ bias,
                                             float* __restrict__ out,
                                             float* __restrict__ outl) {
  __shared__ __align__(16) bf16 As[2][64 * 32];
  __shared__ __align__(16) bf16 Bs[2][256 * 32];
  __shared__ int idxL[64];
  __shared__ float lsred[4];
  const int tid = threadIdx.x;
  const int wid = tid >> 6, lane = tid & 63;
  const int col = lane & 15, quad = lane >> 4;
  const int wm = (wid >> 1) * 32, wn = (wid & 1) * 128;
  const int bm = blockIdx.x * 64, bn = blockIdx.y * 256;
  const bool do_loss = (blockIdx.y == 0);

  // ---- phase 0: combine the 16 group candidates for this block's 64 tokens
  {
    int tl = tid >> 2, j0 = tid & 3;
    float v = 3.4e38f;
    int idx = 0;
#pragma unroll
    for (int jj = 0; jj < 4; jj++) {
      int grp = j0 * 4 + jj;
      float ov = pval[(bm + tl) * GROUPS + grp];
      int oi = pidx[(bm + tl) * GROUPS + grp];
      if (ov < v || (ov == v && oi < idx)) { v = ov; idx = oi; }
    }
#pragma unroll
    for (int off = 1; off < 4; off <<= 1) {
      float ov = __shfl_xor(v, off, 64);
      int oi = __shfl_xor(idx, off, 64);
      if (ov < v || (ov == v && oi < idx)) { v = ov; idx = oi; }
    }
    if (j0 == 0) idxL[tl] = idx;
  }
  __syncthreads();

  const int arow = tid >> 2, ags = tid & 3;
  const int ridx = idxL[arow];
  float lacc = 0.f;
  f32x4 acc[2][8] = {};

  float4 q0, q1;
  auto loadA = [&](int kc) {
    const float* p = cb + (size_t)ridx * EDIM + kc + ags * 8;
    q0 = *(const float4*)p;
    q1 = *(const float4*)(p + 4);
    if (do_loss) {
      u32 zw0 = *(const u32*)(zb8 + (size_t)(bm + arow) * EDIM + kc + ags * 8);
      u32 zw1 = *(const u32*)(zb8 + (size_t)(bm + arow) * EDIM + kc + ags * 8 + 4);
      float d0 = q0.x - __builtin_amdgcn_cvt_f32_fp8(zw0, 0);
      float d1 = q0.y - __builtin_amdgcn_cvt_f32_fp8(zw0, 1);
      float d2 = q0.z - __builtin_amdgcn_cvt_f32_fp8(zw0, 2);
      float d3 = q0.w - __builtin_amdgcn_cvt_f32_fp8(zw0, 3);
      float d4 = q1.x - __builtin_amdgcn_cvt_f32_fp8(zw1, 0);
      float d5 = q1.y - __builtin_amdgcn_cvt_f32_fp8(zw1, 1);
      float d6 = q1.z - __builtin_amdgcn_cvt_f32_fp8(zw1, 2);
      float d7 = q1.w - __builtin_amdgcn_cvt_f32_fp8(zw1, 3);
      lacc += d0 * d0 + d1 * d1 + d2 * d2 + d3 * d3 +
              d4 * d4 + d5 * d5 + d6 * d6 + d7 * d7;
    }
  };
  auto writeA = [&](int bb) {
    bf16x8 o = {(bf16)q0.x, (bf16)q0.y, (bf16)q0.z, (bf16)q0.w,
                (bf16)q1.x, (bf16)q1.y, (bf16)q1.z, (bf16)q1.w};
    *(bf16x8*)((char*)&As[bb][0] + (arow * 4 + (ags ^ (arow & 3))) * 16) = o;
  };
  auto stageB = [&](int kc, int bb) {
#pragma unroll
    for (int j = 0; j < 4; j++) {
      int slot = wid * 256 + j * 64 + lane;
      int row = slot >> 2;
      int gg = (slot & 3) ^ (row & 3);
      async_load16(wT + (size_t)(bn + row) * EDIM + kc + gg * 8,
                   (char*)&Bs[bb][0] + wid * 4096 + j * 1024);
    }
  };

  loadA(0);
  writeA(0);
  stageB(0, 0);
  for (int it = 0; it < 8; it++) {
    int cbuf = it & 1, nbuf = cbuf ^ 1;
    __syncthreads();
    if (it < 7) {
      loadA((it + 1) * 32);
      stageB((it + 1) * 32, nbuf);
    }
    bf16x8 afr[2], bfr[8];
#pragma unroll
    for (int t = 0; t < 2; t++) {
      int row = wm + t * 16 + col;
      afr[t] = *(const bf16x8*)((const char*)&As[cbuf][0] +
                                (row * 4 + (quad ^ (row & 3))) * 16);
    }
#pragma unroll
    for (int u = 0; u < 8; u++) {
      int row = wn + u * 16 + col;
      bfr[u] = *(const bf16x8*)((const char*)&Bs[cbuf][0] +
                                (row * 4 + (quad ^ (row & 3))) * 16);
    }
#pragma unroll
    for (int t = 0; t < 2; t++)
#pragma unroll
      for (int u = 0; u < 8; u++) acc[t][u] = mfma16(afr[t], bfr[u], acc[t][u]);
    if (it < 7) writeA(nbuf);
  }

#pragma unroll
  for (int u = 0; u < 8; u++) {
    int n = bn + wn + u * 16 + col;
    float bv = bias[n];
#pragma unroll
    for (int t = 0; t < 2; t++)
#pragma unroll
      for (int r = 0; r < 4; r++) {
        int m = bm + wm + t * 16 + quad * 4 + r;
        out[(size_t)m * SRC + n] = acc[t][u][r] + bv;
      }
  }

  if (do_loss) {
#pragma unroll
    for (int off = 32; off; off >>= 1) lacc += __shfl_xor(lacc, off, 64);
    if (lane == 0) lsred[wid] = lacc;
    __syncthreads();
    if (tid == 0)
      atomicAdd(outl, 1.25f * (lsred[0] + lsred[1] + lsred[2] + lsred[3]) / LOSS_DENOM);
  }
}

// ---------------- launch ----------------
extern "C" void kernel_launch(void* const* d_in, const int* in_sizes, int n_in,
                              void* d_out, int out_size, void* d_ws, size_t ws_size,
                              hipStream_t stream) {
  const float* x = (const float*)d_in[0];
  const float* enc_w = (const float*)d_in[1];
  const float* enc_b = (const float*)d_in[2];
  const float* cb = (const float*)d_in[3];
  const float* dec_w = (const float*)d_in[4];
  const float* dec_b = (const float*)d_in[5];
  float* out = (float*)d_out;
  float* out_loss = out + (size_t)N_TOK * SRC;

  char* ws = (char*)d_ws;
  bf16* enc_wT = (bf16*)(ws + 0);          //   524,288 B
  bf16* dec_wT = (bf16*)(ws + 524288);     //   524,288 B
  u8* zb8 = (u8*)(ws + 1048576);           // 2,359,296 B
  u32* cbb8 = (u32*)(ws + 3407872);        // 4,194,304 B
  float* e2s = (float*)(ws + 7602176);     //    65,536 B
  float* pval = (float*)(ws + 7667712);    //   589,824 B
  int* pidx = (int*)(ws + 8257536);        //   589,824 B  (~8.8 MiB)

  k_prep<<<4224, 256, 0, stream>>>(enc_w, dec_w, cb, enc_wT, dec_wT, cbb8, e2s, out_loss);
  // encoder: 64x64 tiles BK=64, grid 576, barrier-drain-safe A loads
  k_enc<<<dim3(144, 4), 256, 0, stream>>>(x, enc_wT, enc_b, zb8);
  // fused MX-fp8 K=128 distance + argmin (v8): 768 blocks = exactly 3/CU
  k_argmin<<<dim3(48, GROUPS), 256, 0, stream>>>(zb8, (const u8*)cbb8, e2s, pval, pidx);
  // decoder with fused gather + loss atomicAdd: 64x256 tiles, grid 576
  k_dec<<<dim3(144, 4), 256, 0, stream>>>(cb, pval, pidx, zb8, dec_wT, dec_b, out, out_loss);
}